// Round 7
// baseline (401.808 us; speedup 1.0000x reference)
//
#include <hip/hip_runtime.h>
#include <math.h>

typedef __bf16 bf16x8 __attribute__((ext_vector_type(8)));
typedef __bf16 bf16x4 __attribute__((ext_vector_type(4)));
typedef float f32x4 __attribute__((ext_vector_type(4)));

// ---------------- weight conversion: fp32 -> bf16 frag-major in d_ws ----------
// Frag (kt,nt) = 32x16 block of B; lane L holds B[kt*32+(L>>4)*8+j][nt*16+(L&15)],
// j=0..7 -> one 16B chunk at L*16. Offsets (bf16 units): L1@0 (96x256, 48 frags),
// L2@24576 (256x128, 64), L3@57344 (128x64, 16), L4@65536 (64x128, 16; N 101->128 pad).
// Params packed LINEAR f32 at bf16-offset 73728 (quad index = float/4):
//   0..255 b1 | 256..511 g1 | 512..767 be1 | 768..895 b2 | 896..1023 g2
//   1024..1151 be2 | 1152..1215 b3 | 1216..1279 g3 | 1280..1343 be3
//   1344..1471 b4 (pad 0) | 1472..1599 qsup (pad 0).  Total ws: 153856 B.
__global__ void conv_weights(const float* __restrict__ W1, const float* __restrict__ W2,
                             const float* __restrict__ W3, const float* __restrict__ W4,
                             const float* __restrict__ b1, const float* __restrict__ g1, const float* __restrict__ be1,
                             const float* __restrict__ b2, const float* __restrict__ g2, const float* __restrict__ be2,
                             const float* __restrict__ b3, const float* __restrict__ g3, const float* __restrict__ be3,
                             const float* __restrict__ b4, const float* __restrict__ qsup,
                             __bf16* __restrict__ ws)
{
  if (blockIdx.x == 36) {
    float* Pp = (float*)(ws + 73728);
    const int t = threadIdx.x;
    Pp[t]       = b1[t];
    Pp[256 + t] = g1[t];
    Pp[512 + t] = be1[t];
    if (t < 128) {
      Pp[768 + t]  = b2[t];
      Pp[896 + t]  = g2[t];
      Pp[1024 + t] = be2[t];
      Pp[1344 + t] = (t < 101) ? b4[t]   : 0.f;
      Pp[1472 + t] = (t < 101) ? qsup[t] : 0.f;
    }
    if (t < 64) {
      Pp[1152 + t] = b3[t];
      Pp[1216 + t] = g3[t];
      Pp[1280 + t] = be3[t];
    }
    return;
  }
  const int f = blockIdx.x * 4 + (threadIdx.x >> 6);
  const int lane = threadIdx.x & 63;
  int f0, ntot, Ksrc, Nsrc, off;
  const float* W;
  if (f < 48)       { f0 = f;       ntot = 16; Ksrc = 80;  Nsrc = 256; W = W1; off = 0; }
  else if (f < 112) { f0 = f - 48;  ntot = 8;  Ksrc = 256; Nsrc = 128; W = W2; off = 24576; }
  else if (f < 128) { f0 = f - 112; ntot = 4;  Ksrc = 128; Nsrc = 64;  W = W3; off = 57344; }
  else              { f0 = f - 128; ntot = 8;  Ksrc = 64;  Nsrc = 101; W = W4; off = 65536; }
  const int kt = f0 / ntot, nt = f0 % ntot;
  const int q = lane >> 4, c = lane & 15;
  const int n = nt * 16 + c;
  bf16x8 v;
#pragma unroll
  for (int j = 0; j < 8; ++j) {
    const int k = kt * 32 + q * 8 + j;
    const float x = (k < Ksrc && n < Nsrc) ? W[k * Nsrc + n] : 0.f;
    v[j] = (__bf16)x;
  }
  ((bf16x8*)(ws + off))[f0 * 64 + lane] = v;
}

// ---------------- fused forward: out^T MFMA, 32 rows/wave, spill-free L1 ------
// R6 won -11% via operand-swapped MFMA (weights as A, activations as B ->
// lane-local LN/softmax stats, bf16x4 epilogue stores, branch-free projection)
// but hit the 256-reg unified-file cap in Layer 1 (acc1[2][16]=128 AGPR +
// ~128 arch VGPR) -> ~24 regs spilled to scratch (+23MB WRITE, +9MB FETCH).
// THIS ROUND: L1 processes its two 16-row tiles SEQUENTIALLY (per-rt acc1[16]
// = 64 regs; peak ~166 < 256). Costs one extra pass over L1's 48 weight frags
// (L2-resident); eliminates ~100 scratch ops/thread + 33MB HBM spill traffic.
// L2-L4 keep the dual-rt (32-row) structure — their peaks fit the budget.
//
// Per-wave LDS (floats, stride 4384):
//   h1 [32][264] bf16 = floats [0,4224) (h2 [32][136], h3 [32][72] overlay;
//      layer-k writes ordered after layer-(k-1) reads: alias-conservative
//      compiler order + in-order per-wave DS)
//   proj [32][101] = floats [1152,4384)  (L4 only; h3 [0,1152) disjoint)
// Block = 4*4384*4 = 70144 B -> 2 blocks/CU. Grid B/128 = 1024.

__global__ __launch_bounds__(256, 2)
void sacq_wave(const float* __restrict__ obs,  const float* __restrict__ act,
               const float* __restrict__ rew,  const float* __restrict__ boot,
               const float* __restrict__ disc, const float* __restrict__ qsup,
               const float* __restrict__ b1, const float* __restrict__ g1, const float* __restrict__ be1,
               const float* __restrict__ b2, const float* __restrict__ g2, const float* __restrict__ be2,
               const float* __restrict__ b3, const float* __restrict__ g3, const float* __restrict__ be3,
               const float* __restrict__ b4,
               const __bf16* __restrict__ ws,
               float* __restrict__ out)
{
  __shared__ float sm[17536];
  const int t = threadIdx.x;
  const int wv = t >> 6, lane = t & 63;
  const int q = lane >> 4, c = lane & 15;
  float* smw = sm + wv * 4384;
  __bf16* h = (__bf16*)smw;               // h1/h2/h3 overlay
  float* proj = smw + 1152;               // [32][101] (L4 only)
  const int row0w = blockIdx.x * 128 + wv * 32;
  const bf16x8* wsf = (const bf16x8*)ws;
  const f32x4* P4 = (const f32x4*)(const void*)(ws + 73728);
  const int fq = 4 * q;                   // feature sub-offset within an m-tile

  // ================= Layer 1: out^T[256][32] = W1^T @ x^T, LN+SiLU ==========
  // Sequential over the two 16-row tiles to keep register peak ~166 (<256).
#pragma unroll 1
  for (int rt = 0; rt < 2; ++rt) {
    bf16x8 A1[3];   // this rt's activation fragments (B operand)
    {
      const float4* ob4 = (const float4*)(obs + (size_t)(row0w + rt * 16 + c) * 60);
      const float4* ac4 = (const float4*)(act + (size_t)(row0w + rt * 16 + c) * 20);
#pragma unroll
      for (int kt = 0; kt < 3; ++kt) {
        const int k0 = kt * 32 + q * 8;
        float v[8];
        if (k0 < 56) {
          const float4 a = ob4[k0 / 4], b = ob4[k0 / 4 + 1];
          v[0]=a.x; v[1]=a.y; v[2]=a.z; v[3]=a.w; v[4]=b.x; v[5]=b.y; v[6]=b.z; v[7]=b.w;
        } else if (k0 == 56) {
          const float4 a = ob4[14], b = ac4[0];
          v[0]=a.x; v[1]=a.y; v[2]=a.z; v[3]=a.w; v[4]=b.x; v[5]=b.y; v[6]=b.z; v[7]=b.w;
        } else if (k0 < 80) {
          const float4 a = ac4[(k0 - 60) / 4], b = ac4[(k0 - 60) / 4 + 1];
          v[0]=a.x; v[1]=a.y; v[2]=a.z; v[3]=a.w; v[4]=b.x; v[5]=b.y; v[6]=b.z; v[7]=b.w;
        } else {
#pragma unroll
          for (int j = 0; j < 8; ++j) v[j] = 0.f;
        }
#pragma unroll
        for (int j = 0; j < 8; ++j) A1[kt][j] = (__bf16)v[j];
      }
    }
    f32x4 acc1[16];
#pragma unroll
    for (int mt = 0; mt < 16; ++mt) acc1[mt] = P4[4 * mt + q];
    // 4 chunks of 4 m-tiles; each chunk: 12 W-frag loads, then 12 MFMAs
#pragma unroll
    for (int ch = 0; ch < 4; ++ch) {
      bf16x8 Wb[3][4];
#pragma unroll
      for (int kt = 0; kt < 3; ++kt)
#pragma unroll
        for (int j = 0; j < 4; ++j)
          Wb[kt][j] = wsf[(kt * 16 + ch * 4 + j) * 64 + lane];
#pragma unroll
      for (int kt = 0; kt < 3; ++kt)
#pragma unroll
        for (int j = 0; j < 4; ++j)
          acc1[ch * 4 + j] = __builtin_amdgcn_mfma_f32_16x16x32_bf16(Wb[kt][j], A1[kt], acc1[ch * 4 + j], 0, 0, 0);
    }
    // LN stats: lane-local over 64 features + butterfly over q-lanes (2 shfl)
    float s = 0.f, s2 = 0.f;
#pragma unroll
    for (int mt = 0; mt < 16; ++mt)
#pragma unroll
      for (int r = 0; r < 4; ++r) { const float v = acc1[mt][r]; s += v; s2 += v * v; }
    s += __shfl_xor(s, 16); s2 += __shfl_xor(s2, 16);
    s += __shfl_xor(s, 32); s2 += __shfl_xor(s2, 32);
    const float mu = s * (1.f / 256.f);
    const float rs = rsqrtf(s2 * (1.f / 256.f) - mu * mu + 1e-5f);
#pragma unroll
    for (int mt = 0; mt < 16; ++mt) {
      const f32x4 g4  = P4[64 + 4 * mt + q];
      const f32x4 be4 = P4[128 + 4 * mt + q];
      bf16x4 o;
#pragma unroll
      for (int r = 0; r < 4; ++r) {
        float x = (acc1[mt][r] - mu) * rs * g4[r] + be4[r];
        x = x * __builtin_amdgcn_rcpf(1.f + __expf(-x));
        o[r] = (__bf16)x;
      }
      *(bf16x4*)(h + (rt * 16 + c) * 264 + 16 * mt + fq) = o;
    }
  }

  // ================= Layer 2: out^T[128][32] = W2^T @ h1^T, LN+SiLU =========
  {
    f32x4 acc2[2][8];
#pragma unroll
    for (int mt = 0; mt < 8; ++mt) {
      const f32x4 pb = P4[192 + 4 * mt + q];
      acc2[0][mt] = pb;
      acc2[1][mt] = pb;
    }
    bf16x8 W2f[2][8];
#pragma unroll
    for (int mt = 0; mt < 8; ++mt) W2f[0][mt] = wsf[3072 + mt * 64 + lane];
#pragma unroll
    for (int kt = 0; kt < 8; ++kt) {
      if (kt + 1 < 8) {
#pragma unroll
        for (int mt = 0; mt < 8; ++mt)
          W2f[(kt + 1) & 1][mt] = wsf[3072 + ((kt + 1) * 8 + mt) * 64 + lane];
      }
      bf16x8 A2r[2];
#pragma unroll
      for (int rt = 0; rt < 2; ++rt)
        A2r[rt] = *(const bf16x8*)(h + (rt * 16 + c) * 264 + kt * 32 + q * 8);
#pragma unroll
      for (int mt = 0; mt < 8; ++mt)
#pragma unroll
        for (int rt = 0; rt < 2; ++rt)
          acc2[rt][mt] = __builtin_amdgcn_mfma_f32_16x16x32_bf16(W2f[kt & 1][mt], A2r[rt], acc2[rt][mt], 0, 0, 0);
    }
#pragma unroll
    for (int rt = 0; rt < 2; ++rt) {
      float s = 0.f, s2 = 0.f;
#pragma unroll
      for (int mt = 0; mt < 8; ++mt)
#pragma unroll
        for (int r = 0; r < 4; ++r) { const float v = acc2[rt][mt][r]; s += v; s2 += v * v; }
      s += __shfl_xor(s, 16); s2 += __shfl_xor(s2, 16);
      s += __shfl_xor(s, 32); s2 += __shfl_xor(s2, 32);
      const float mu = s * (1.f / 128.f);
      const float rs = rsqrtf(s2 * (1.f / 128.f) - mu * mu + 1e-5f);
#pragma unroll
      for (int mt = 0; mt < 8; ++mt) {
        const f32x4 g4  = P4[224 + 4 * mt + q];
        const f32x4 be4 = P4[256 + 4 * mt + q];
        bf16x4 o;
#pragma unroll
        for (int r = 0; r < 4; ++r) {
          float x = (acc2[rt][mt][r] - mu) * rs * g4[r] + be4[r];
          x = x * __builtin_amdgcn_rcpf(1.f + __expf(-x));
          o[r] = (__bf16)x;
        }
        *(bf16x4*)(h + (rt * 16 + c) * 136 + 16 * mt + fq) = o;
      }
    }
  }

  // ================= Layer 3: out^T[64][32] = W3^T @ h2^T, LN+SiLU ==========
  {
    bf16x8 W3f[4][4];
#pragma unroll
    for (int kt = 0; kt < 4; ++kt)
#pragma unroll
      for (int mt = 0; mt < 4; ++mt)
        W3f[kt][mt] = wsf[7168 + (kt * 4 + mt) * 64 + lane];
    f32x4 acc3[2][4];
#pragma unroll
    for (int mt = 0; mt < 4; ++mt) {
      const f32x4 pb = P4[288 + 4 * mt + q];
      acc3[0][mt] = pb;
      acc3[1][mt] = pb;
    }
#pragma unroll
    for (int kt = 0; kt < 4; ++kt) {
      bf16x8 A3r[2];
#pragma unroll
      for (int rt = 0; rt < 2; ++rt)
        A3r[rt] = *(const bf16x8*)(h + (rt * 16 + c) * 136 + kt * 32 + q * 8);
#pragma unroll
      for (int mt = 0; mt < 4; ++mt)
#pragma unroll
        for (int rt = 0; rt < 2; ++rt)
          acc3[rt][mt] = __builtin_amdgcn_mfma_f32_16x16x32_bf16(W3f[kt][mt], A3r[rt], acc3[rt][mt], 0, 0, 0);
    }
#pragma unroll
    for (int rt = 0; rt < 2; ++rt) {
      float s = 0.f, s2 = 0.f;
#pragma unroll
      for (int mt = 0; mt < 4; ++mt)
#pragma unroll
        for (int r = 0; r < 4; ++r) { const float v = acc3[rt][mt][r]; s += v; s2 += v * v; }
      s += __shfl_xor(s, 16); s2 += __shfl_xor(s2, 16);
      s += __shfl_xor(s, 32); s2 += __shfl_xor(s2, 32);
      const float mu = s * (1.f / 64.f);
      const float rs = rsqrtf(s2 * (1.f / 64.f) - mu * mu + 1e-5f);
#pragma unroll
      for (int mt = 0; mt < 4; ++mt) {
        const f32x4 g4  = P4[304 + 4 * mt + q];
        const f32x4 be4 = P4[320 + 4 * mt + q];
        bf16x4 o;
#pragma unroll
        for (int r = 0; r < 4; ++r) {
          float x = (acc3[rt][mt][r] - mu) * rs * g4[r] + be4[r];
          x = x * __builtin_amdgcn_rcpf(1.f + __expf(-x));
          o[r] = (__bf16)x;
        }
        *(bf16x4*)(h + (rt * 16 + c) * 72 + 16 * mt + fq) = o;
      }
    }
  }

  // ================= Layer 4 (101 feats) + softmax + projection =============
  {
    bf16x8 W4f[2][7];
#pragma unroll
    for (int kt = 0; kt < 2; ++kt)
#pragma unroll
      for (int mt = 0; mt < 7; ++mt)
        W4f[kt][mt] = wsf[8192 + (kt * 8 + mt) * 64 + lane];
    bf16x8 A4f[2][2];
#pragma unroll
    for (int rt = 0; rt < 2; ++rt)
#pragma unroll
      for (int kt = 0; kt < 2; ++kt)
        A4f[rt][kt] = *(const bf16x8*)(h + (rt * 16 + c) * 72 + kt * 32 + q * 8);

    // Fence, then zero proj (proj [1152,4384) overlays only dead h1/h2 region;
    // live h3 [0,1152) disjoint; keep stores ordered after the A4f reads).
    asm volatile("" ::: "memory");
    {
      f32x4 z = {0.f, 0.f, 0.f, 0.f};
      f32x4* p4 = (f32x4*)proj;
      for (int i = lane; i < 808; i += 64) p4[i] = z;
    }

    f32x4 a4[2][7];
#pragma unroll
    for (int mt = 0; mt < 7; ++mt) {
      const f32x4 pb = P4[336 + 4 * mt + q];
      a4[0][mt] = pb;
      a4[1][mt] = pb;
    }
#pragma unroll
    for (int kt = 0; kt < 2; ++kt)
#pragma unroll
      for (int mt = 0; mt < 7; ++mt)
#pragma unroll
        for (int rt = 0; rt < 2; ++rt)
          a4[rt][mt] = __builtin_amdgcn_mfma_f32_16x16x32_bf16(W4f[kt][mt], A4f[rt][kt], a4[rt][mt], 0, 0, 0);

#pragma unroll
    for (int rt = 0; rt < 2; ++rt) {
      // softmax over the 101 features of this lane's batch row (lane-local + 2 shfl)
      float mx = -3.4e38f;
#pragma unroll
      for (int mt = 0; mt < 7; ++mt) {
#pragma unroll
        for (int r = 0; r < 4; ++r) {
          const bool ok = (mt < 6) | (fq + r < 5);
          if (ok) mx = fmaxf(mx, a4[rt][mt][r]);
        }
      }
      mx = fmaxf(mx, __shfl_xor(mx, 16));
      mx = fmaxf(mx, __shfl_xor(mx, 32));
      float sp = 0.f;
#pragma unroll
      for (int mt = 0; mt < 7; ++mt) {
#pragma unroll
        for (int r = 0; r < 4; ++r) {
          const bool ok = (mt < 6) | (fq + r < 5);
          const float e = ok ? __expf(a4[rt][mt][r] - mx) : 0.f;
          a4[rt][mt][r] = e;
          sp += e;
        }
      }
      sp += __shfl_xor(sp, 16);
      sp += __shfl_xor(sp, 32);
      const float inv = __builtin_amdgcn_rcpf(sp);

      const int gr = row0w + rt * 16 + c;
      const float rw = rew[gr];
      const float bd = boot[gr] * disc[gr];
      const int rb = (rt * 16 + c) * 101;

      // categorical projection (branch-free index math; li in [0,99])
#pragma unroll
      for (int mt = 0; mt < 7; ++mt) {
        const f32x4 qs4 = P4[368 + 4 * mt + q];
#pragma unroll
        for (int r = 0; r < 4; ++r) {
          const bool ok = (mt < 6) | (fq + r < 5);
          if (ok) {
            const float p = a4[rt][mt][r] * inv;
            float tz = rw + bd * qs4[r];
            tz = fminf(fmaxf(tz, -10.f), 10.f);
            const float b_ = tz * 5.f + 50.f;            // in [0,100]
            const float fl = fminf(floorf(b_), 99.f);    // in [0,99]
            const float frac = b_ - fl;                  // in [0,1]
            const float uw = p * frac;
            const float lw = p - uw;
            const int li = (int)fl;
            atomicAdd(&proj[rb + li], lw);
            atomicAdd(&proj[rb + li + 1], uw);
          }
        }
      }
    }
  }

  // ---- coalesced float4 writeout of this wave's 32x101 block
  {
    const f32x4* p4 = (const f32x4*)proj;
    f32x4* o4 = (f32x4*)(out + (size_t)row0w * 101);
    for (int i = lane; i < 808; i += 64) o4[i] = p4[i];
  }
}

extern "C" void kernel_launch(void* const* d_in, const int* in_sizes, int n_in,
                              void* d_out, int out_size, void* d_ws, size_t ws_size,
                              hipStream_t stream)
{
  const int B = in_sizes[2];  // rewards: B elements
  __bf16* ws = (__bf16*)d_ws; // 153856 B used

  conv_weights<<<dim3(37), dim3(256), 0, stream>>>(
      (const float*)d_in[6],  (const float*)d_in[10], (const float*)d_in[14],
      (const float*)d_in[18],
      (const float*)d_in[7],  (const float*)d_in[8],  (const float*)d_in[9],
      (const float*)d_in[11], (const float*)d_in[12], (const float*)d_in[13],
      (const float*)d_in[15], (const float*)d_in[16], (const float*)d_in[17],
      (const float*)d_in[19], (const float*)d_in[5],  ws);

  sacq_wave<<<dim3(B / 128), dim3(256), 0, stream>>>(
      (const float*)d_in[0],  (const float*)d_in[1],  (const float*)d_in[2],
      (const float*)d_in[3],  (const float*)d_in[4],  (const float*)d_in[5],
      (const float*)d_in[7],  (const float*)d_in[8],  (const float*)d_in[9],
      (const float*)d_in[11], (const float*)d_in[12], (const float*)d_in[13],
      (const float*)d_in[15], (const float*)d_in[16], (const float*)d_in[17],
      (const float*)d_in[19], ws, (float*)d_out);
}

// Round 8
// 307.099 us; speedup vs baseline: 1.3084x; 1.3084x over previous
//
#include <hip/hip_runtime.h>
#include <math.h>

typedef __bf16 bf16x8 __attribute__((ext_vector_type(8)));
typedef __bf16 bf16x4 __attribute__((ext_vector_type(4)));
typedef float f32x4 __attribute__((ext_vector_type(4)));

// ---------------- weight conversion: fp32 -> bf16 frag-major in d_ws ----------
// Frag (kt,nt) = 32x16 block of B; lane L holds B[kt*32+(L>>4)*8+j][nt*16+(L&15)],
// j=0..7 -> one 16B chunk at L*16. Offsets (bf16 units): L1@0 (96x256, 48 frags),
// L2@24576 (256x128, 64), L3@57344 (128x64, 16), L4@65536 (64x128, 16; N 101->128 pad).
// Params packed LINEAR f32 at bf16-offset 73728 (quad index = float/4):
//   0..255 b1 | 256..511 g1 | 512..767 be1 | 768..895 b2 | 896..1023 g2
//   1024..1151 be2 | 1152..1215 b3 | 1216..1279 g3 | 1280..1343 be3
//   1344..1471 b4 (pad 0) | 1472..1599 qsup (pad 0).  Total ws: 153856 B.
__global__ void conv_weights(const float* __restrict__ W1, const float* __restrict__ W2,
                             const float* __restrict__ W3, const float* __restrict__ W4,
                             const float* __restrict__ b1, const float* __restrict__ g1, const float* __restrict__ be1,
                             const float* __restrict__ b2, const float* __restrict__ g2, const float* __restrict__ be2,
                             const float* __restrict__ b3, const float* __restrict__ g3, const float* __restrict__ be3,
                             const float* __restrict__ b4, const float* __restrict__ qsup,
                             __bf16* __restrict__ ws)
{
  if (blockIdx.x == 36) {
    float* Pp = (float*)(ws + 73728);
    const int t = threadIdx.x;
    Pp[t]       = b1[t];
    Pp[256 + t] = g1[t];
    Pp[512 + t] = be1[t];
    if (t < 128) {
      Pp[768 + t]  = b2[t];
      Pp[896 + t]  = g2[t];
      Pp[1024 + t] = be2[t];
      Pp[1344 + t] = (t < 101) ? b4[t]   : 0.f;
      Pp[1472 + t] = (t < 101) ? qsup[t] : 0.f;
    }
    if (t < 64) {
      Pp[1152 + t] = b3[t];
      Pp[1216 + t] = g3[t];
      Pp[1280 + t] = be3[t];
    }
    return;
  }
  const int f = blockIdx.x * 4 + (threadIdx.x >> 6);
  const int lane = threadIdx.x & 63;
  int f0, ntot, Ksrc, Nsrc, off;
  const float* W;
  if (f < 48)       { f0 = f;       ntot = 16; Ksrc = 80;  Nsrc = 256; W = W1; off = 0; }
  else if (f < 112) { f0 = f - 48;  ntot = 8;  Ksrc = 256; Nsrc = 128; W = W2; off = 24576; }
  else if (f < 128) { f0 = f - 112; ntot = 4;  Ksrc = 128; Nsrc = 64;  W = W3; off = 57344; }
  else              { f0 = f - 128; ntot = 8;  Ksrc = 64;  Nsrc = 101; W = W4; off = 65536; }
  const int kt = f0 / ntot, nt = f0 % ntot;
  const int q = lane >> 4, c = lane & 15;
  const int n = nt * 16 + c;
  bf16x8 v;
#pragma unroll
  for (int j = 0; j < 8; ++j) {
    const int k = kt * 32 + q * 8 + j;
    const float x = (k < Ksrc && n < Nsrc) ? W[k * Nsrc + n] : 0.f;
    v[j] = (__bf16)x;
  }
  ((bf16x8*)(ws + off))[f0 * 64 + lane] = v;
}

// ---------------- fused forward: out^T MFMA, 32 rows/wave (R6 base) -----------
// R6 (202.9us, best) = operand-swapped MFMA (weights as A, activations as B ->
// lane-local LN/softmax stats, bf16x4 epilogue stores, branch-free projection),
// dual row-tile everywhere. Its one defect: L1 peak (acc1 128 + Wb 48 + A1 24
// + addressing ~ 250-280) exceeded the 256-unified-reg cap -> ~24-reg spill
// (+23MB WRITE / +9MB FETCH). R7's rolled-rt "fix" wrecked regalloc (310MB
// spill) — rolled loops around MFMA accumulators are poison on this compiler.
// THIS ROUND: R6 verbatim except L1's weight burst shrinks from Wb[3][4]
// (48 regs, 4 chunks) to Wb[3][2] (24 regs, 8 chunks) — removes exactly the
// estimated overflow while keeping full unroll. Burst depth 6 still covers
// L2-resident latency under 8-wave TLP.
//
// Per-wave LDS (floats, stride 4384):
//   h1 [32][264] bf16 = floats [0,4224) (h2 [32][136], h3 [32][72] overlay;
//      layer-k writes ordered after layer-(k-1) reads: alias-conservative
//      compiler order + in-order per-wave DS)
//   proj [32][101] = floats [1152,4384)  (L4 only; h3 [0,1152) disjoint)
// Block = 4*4384*4 = 70144 B -> 2 blocks/CU. Grid B/128 = 1024.

__global__ __launch_bounds__(256, 2)
void sacq_wave(const float* __restrict__ obs,  const float* __restrict__ act,
               const float* __restrict__ rew,  const float* __restrict__ boot,
               const float* __restrict__ disc, const float* __restrict__ qsup,
               const float* __restrict__ b1, const float* __restrict__ g1, const float* __restrict__ be1,
               const float* __restrict__ b2, const float* __restrict__ g2, const float* __restrict__ be2,
               const float* __restrict__ b3, const float* __restrict__ g3, const float* __restrict__ be3,
               const float* __restrict__ b4,
               const __bf16* __restrict__ ws,
               float* __restrict__ out)
{
  __shared__ float sm[17536];
  const int t = threadIdx.x;
  const int wv = t >> 6, lane = t & 63;
  const int q = lane >> 4, c = lane & 15;
  float* smw = sm + wv * 4384;
  __bf16* h = (__bf16*)smw;               // h1/h2/h3 overlay
  float* proj = smw + 1152;               // [32][101] (L4 only)
  const int row0w = blockIdx.x * 128 + wv * 32;
  const bf16x8* wsf = (const bf16x8*)ws;
  const f32x4* P4 = (const f32x4*)(const void*)(ws + 73728);
  const int fq = 4 * q;                   // feature sub-offset within an m-tile

  // ================= Layer 1: out^T[256][32] = W1^T @ x^T, LN+SiLU ==========
  f32x4 acc1[2][16];
  {
    bf16x8 A1[2][3];   // activation fragments (B operand): lane c holds row c
#pragma unroll
    for (int rt = 0; rt < 2; ++rt) {
      const float4* ob4 = (const float4*)(obs + (size_t)(row0w + rt * 16 + c) * 60);
      const float4* ac4 = (const float4*)(act + (size_t)(row0w + rt * 16 + c) * 20);
#pragma unroll
      for (int kt = 0; kt < 3; ++kt) {
        const int k0 = kt * 32 + q * 8;
        float v[8];
        if (k0 < 56) {
          const float4 a = ob4[k0 / 4], b = ob4[k0 / 4 + 1];
          v[0]=a.x; v[1]=a.y; v[2]=a.z; v[3]=a.w; v[4]=b.x; v[5]=b.y; v[6]=b.z; v[7]=b.w;
        } else if (k0 == 56) {
          const float4 a = ob4[14], b = ac4[0];
          v[0]=a.x; v[1]=a.y; v[2]=a.z; v[3]=a.w; v[4]=b.x; v[5]=b.y; v[6]=b.z; v[7]=b.w;
        } else if (k0 < 80) {
          const float4 a = ac4[(k0 - 60) / 4], b = ac4[(k0 - 60) / 4 + 1];
          v[0]=a.x; v[1]=a.y; v[2]=a.z; v[3]=a.w; v[4]=b.x; v[5]=b.y; v[6]=b.z; v[7]=b.w;
        } else {
#pragma unroll
          for (int j = 0; j < 8; ++j) v[j] = 0.f;
        }
#pragma unroll
        for (int j = 0; j < 8; ++j) A1[rt][kt][j] = (__bf16)v[j];
      }
    }
    // acc init with bias: acc[rt][mt][r] = b1[16mt+4q+r] -> one f32x4 per mt
#pragma unroll
    for (int mt = 0; mt < 16; ++mt) {
      const f32x4 pb = P4[4 * mt + q];
      acc1[0][mt] = pb;
      acc1[1][mt] = pb;
    }
    // 8 chunks of 2 m-tiles; each chunk: 6 W-frag loads (24 regs), 12 MFMAs
#pragma unroll
    for (int ch = 0; ch < 8; ++ch) {
      bf16x8 Wb[3][2];
#pragma unroll
      for (int kt = 0; kt < 3; ++kt)
#pragma unroll
        for (int j = 0; j < 2; ++j)
          Wb[kt][j] = wsf[(kt * 16 + ch * 2 + j) * 64 + lane];
#pragma unroll
      for (int kt = 0; kt < 3; ++kt)
#pragma unroll
        for (int j = 0; j < 2; ++j)
#pragma unroll
          for (int rt = 0; rt < 2; ++rt)
            acc1[rt][ch * 2 + j] = __builtin_amdgcn_mfma_f32_16x16x32_bf16(Wb[kt][j], A1[rt][kt], acc1[rt][ch * 2 + j], 0, 0, 0);
    }
    // LN stats: lane-local over 64 features + butterfly over q-lanes (2 shfl)
#pragma unroll
    for (int rt = 0; rt < 2; ++rt) {
      float s = 0.f, s2 = 0.f;
#pragma unroll
      for (int mt = 0; mt < 16; ++mt)
#pragma unroll
        for (int r = 0; r < 4; ++r) { const float v = acc1[rt][mt][r]; s += v; s2 += v * v; }
      s += __shfl_xor(s, 16); s2 += __shfl_xor(s2, 16);
      s += __shfl_xor(s, 32); s2 += __shfl_xor(s2, 32);
      const float mu = s * (1.f / 256.f);
      const float rs = rsqrtf(s2 * (1.f / 256.f) - mu * mu + 1e-5f);
#pragma unroll
      for (int mt = 0; mt < 16; ++mt) {
        const f32x4 g4  = P4[64 + 4 * mt + q];
        const f32x4 be4 = P4[128 + 4 * mt + q];
        bf16x4 o;
#pragma unroll
        for (int r = 0; r < 4; ++r) {
          float x = (acc1[rt][mt][r] - mu) * rs * g4[r] + be4[r];
          x = x * __builtin_amdgcn_rcpf(1.f + __expf(-x));
          o[r] = (__bf16)x;
        }
        *(bf16x4*)(h + (rt * 16 + c) * 264 + 16 * mt + fq) = o;
      }
    }
  }

  // ================= Layer 2: out^T[128][32] = W2^T @ h1^T, LN+SiLU =========
  {
    f32x4 acc2[2][8];
#pragma unroll
    for (int mt = 0; mt < 8; ++mt) {
      const f32x4 pb = P4[192 + 4 * mt + q];
      acc2[0][mt] = pb;
      acc2[1][mt] = pb;
    }
    bf16x8 W2f[2][8];
#pragma unroll
    for (int mt = 0; mt < 8; ++mt) W2f[0][mt] = wsf[3072 + mt * 64 + lane];
#pragma unroll
    for (int kt = 0; kt < 8; ++kt) {
      if (kt + 1 < 8) {
#pragma unroll
        for (int mt = 0; mt < 8; ++mt)
          W2f[(kt + 1) & 1][mt] = wsf[3072 + ((kt + 1) * 8 + mt) * 64 + lane];
      }
      bf16x8 A2r[2];
#pragma unroll
      for (int rt = 0; rt < 2; ++rt)
        A2r[rt] = *(const bf16x8*)(h + (rt * 16 + c) * 264 + kt * 32 + q * 8);
#pragma unroll
      for (int mt = 0; mt < 8; ++mt)
#pragma unroll
        for (int rt = 0; rt < 2; ++rt)
          acc2[rt][mt] = __builtin_amdgcn_mfma_f32_16x16x32_bf16(W2f[kt & 1][mt], A2r[rt], acc2[rt][mt], 0, 0, 0);
    }
#pragma unroll
    for (int rt = 0; rt < 2; ++rt) {
      float s = 0.f, s2 = 0.f;
#pragma unroll
      for (int mt = 0; mt < 8; ++mt)
#pragma unroll
        for (int r = 0; r < 4; ++r) { const float v = acc2[rt][mt][r]; s += v; s2 += v * v; }
      s += __shfl_xor(s, 16); s2 += __shfl_xor(s2, 16);
      s += __shfl_xor(s, 32); s2 += __shfl_xor(s2, 32);
      const float mu = s * (1.f / 128.f);
      const float rs = rsqrtf(s2 * (1.f / 128.f) - mu * mu + 1e-5f);
#pragma unroll
      for (int mt = 0; mt < 8; ++mt) {
        const f32x4 g4  = P4[224 + 4 * mt + q];
        const f32x4 be4 = P4[256 + 4 * mt + q];
        bf16x4 o;
#pragma unroll
        for (int r = 0; r < 4; ++r) {
          float x = (acc2[rt][mt][r] - mu) * rs * g4[r] + be4[r];
          x = x * __builtin_amdgcn_rcpf(1.f + __expf(-x));
          o[r] = (__bf16)x;
        }
        *(bf16x4*)(h + (rt * 16 + c) * 136 + 16 * mt + fq) = o;
      }
    }
  }

  // ================= Layer 3: out^T[64][32] = W3^T @ h2^T, LN+SiLU ==========
  {
    bf16x8 W3f[4][4];
#pragma unroll
    for (int kt = 0; kt < 4; ++kt)
#pragma unroll
      for (int mt = 0; mt < 4; ++mt)
        W3f[kt][mt] = wsf[7168 + (kt * 4 + mt) * 64 + lane];
    f32x4 acc3[2][4];
#pragma unroll
    for (int mt = 0; mt < 4; ++mt) {
      const f32x4 pb = P4[288 + 4 * mt + q];
      acc3[0][mt] = pb;
      acc3[1][mt] = pb;
    }
#pragma unroll
    for (int kt = 0; kt < 4; ++kt) {
      bf16x8 A3r[2];
#pragma unroll
      for (int rt = 0; rt < 2; ++rt)
        A3r[rt] = *(const bf16x8*)(h + (rt * 16 + c) * 136 + kt * 32 + q * 8);
#pragma unroll
      for (int mt = 0; mt < 4; ++mt)
#pragma unroll
        for (int rt = 0; rt < 2; ++rt)
          acc3[rt][mt] = __builtin_amdgcn_mfma_f32_16x16x32_bf16(W3f[kt][mt], A3r[rt], acc3[rt][mt], 0, 0, 0);
    }
#pragma unroll
    for (int rt = 0; rt < 2; ++rt) {
      float s = 0.f, s2 = 0.f;
#pragma unroll
      for (int mt = 0; mt < 4; ++mt)
#pragma unroll
        for (int r = 0; r < 4; ++r) { const float v = acc3[rt][mt][r]; s += v; s2 += v * v; }
      s += __shfl_xor(s, 16); s2 += __shfl_xor(s2, 16);
      s += __shfl_xor(s, 32); s2 += __shfl_xor(s2, 32);
      const float mu = s * (1.f / 64.f);
      const float rs = rsqrtf(s2 * (1.f / 64.f) - mu * mu + 1e-5f);
#pragma unroll
      for (int mt = 0; mt < 4; ++mt) {
        const f32x4 g4  = P4[304 + 4 * mt + q];
        const f32x4 be4 = P4[320 + 4 * mt + q];
        bf16x4 o;
#pragma unroll
        for (int r = 0; r < 4; ++r) {
          float x = (acc3[rt][mt][r] - mu) * rs * g4[r] + be4[r];
          x = x * __builtin_amdgcn_rcpf(1.f + __expf(-x));
          o[r] = (__bf16)x;
        }
        *(bf16x4*)(h + (rt * 16 + c) * 72 + 16 * mt + fq) = o;
      }
    }
  }

  // ================= Layer 4 (101 feats) + softmax + projection =============
  {
    bf16x8 W4f[2][7];
#pragma unroll
    for (int kt = 0; kt < 2; ++kt)
#pragma unroll
      for (int mt = 0; mt < 7; ++mt)
        W4f[kt][mt] = wsf[8192 + (kt * 8 + mt) * 64 + lane];
    bf16x8 A4f[2][2];
#pragma unroll
    for (int rt = 0; rt < 2; ++rt)
#pragma unroll
      for (int kt = 0; kt < 2; ++kt)
        A4f[rt][kt] = *(const bf16x8*)(h + (rt * 16 + c) * 72 + kt * 32 + q * 8);

    // Fence, then zero proj (proj [1152,4384) overlays only dead h1/h2 region;
    // live h3 [0,1152) disjoint; keep stores ordered after the A4f reads).
    asm volatile("" ::: "memory");
    {
      f32x4 z = {0.f, 0.f, 0.f, 0.f};
      f32x4* p4 = (f32x4*)proj;
      for (int i = lane; i < 808; i += 64) p4[i] = z;
    }

    f32x4 a4[2][7];
#pragma unroll
    for (int mt = 0; mt < 7; ++mt) {
      const f32x4 pb = P4[336 + 4 * mt + q];
      a4[0][mt] = pb;
      a4[1][mt] = pb;
    }
#pragma unroll
    for (int kt = 0; kt < 2; ++kt)
#pragma unroll
      for (int mt = 0; mt < 7; ++mt)
#pragma unroll
        for (int rt = 0; rt < 2; ++rt)
          a4[rt][mt] = __builtin_amdgcn_mfma_f32_16x16x32_bf16(W4f[kt][mt], A4f[rt][kt], a4[rt][mt], 0, 0, 0);

#pragma unroll
    for (int rt = 0; rt < 2; ++rt) {
      // softmax over the 101 features of this lane's batch row (lane-local + 2 shfl)
      float mx = -3.4e38f;
#pragma unroll
      for (int mt = 0; mt < 7; ++mt) {
#pragma unroll
        for (int r = 0; r < 4; ++r) {
          const bool ok = (mt < 6) | (fq + r < 5);
          if (ok) mx = fmaxf(mx, a4[rt][mt][r]);
        }
      }
      mx = fmaxf(mx, __shfl_xor(mx, 16));
      mx = fmaxf(mx, __shfl_xor(mx, 32));
      float sp = 0.f;
#pragma unroll
      for (int mt = 0; mt < 7; ++mt) {
#pragma unroll
        for (int r = 0; r < 4; ++r) {
          const bool ok = (mt < 6) | (fq + r < 5);
          const float e = ok ? __expf(a4[rt][mt][r] - mx) : 0.f;
          a4[rt][mt][r] = e;
          sp += e;
        }
      }
      sp += __shfl_xor(sp, 16);
      sp += __shfl_xor(sp, 32);
      const float inv = __builtin_amdgcn_rcpf(sp);

      const int gr = row0w + rt * 16 + c;
      const float rw = rew[gr];
      const float bd = boot[gr] * disc[gr];
      const int rb = (rt * 16 + c) * 101;

      // categorical projection (branch-free index math; li in [0,99])
#pragma unroll
      for (int mt = 0; mt < 7; ++mt) {
        const f32x4 qs4 = P4[368 + 4 * mt + q];
#pragma unroll
        for (int r = 0; r < 4; ++r) {
          const bool ok = (mt < 6) | (fq + r < 5);
          if (ok) {
            const float p = a4[rt][mt][r] * inv;
            float tz = rw + bd * qs4[r];
            tz = fminf(fmaxf(tz, -10.f), 10.f);
            const float b_ = tz * 5.f + 50.f;            // in [0,100]
            const float fl = fminf(floorf(b_), 99.f);    // in [0,99]
            const float frac = b_ - fl;                  // in [0,1]
            const float uw = p * frac;
            const float lw = p - uw;
            const int li = (int)fl;
            atomicAdd(&proj[rb + li], lw);
            atomicAdd(&proj[rb + li + 1], uw);
          }
        }
      }
    }
  }

  // ---- coalesced float4 writeout of this wave's 32x101 block
  {
    const f32x4* p4 = (const f32x4*)proj;
    f32x4* o4 = (f32x4*)(out + (size_t)row0w * 101);
    for (int i = lane; i < 808; i += 64) o4[i] = p4[i];
  }
}

extern "C" void kernel_launch(void* const* d_in, const int* in_sizes, int n_in,
                              void* d_out, int out_size, void* d_ws, size_t ws_size,
                              hipStream_t stream)
{
  const int B = in_sizes[2];  // rewards: B elements
  __bf16* ws = (__bf16*)d_ws; // 153856 B used

  conv_weights<<<dim3(37), dim3(256), 0, stream>>>(
      (const float*)d_in[6],  (const float*)d_in[10], (const float*)d_in[14],
      (const float*)d_in[18],
      (const float*)d_in[7],  (const float*)d_in[8],  (const float*)d_in[9],
      (const float*)d_in[11], (const float*)d_in[12], (const float*)d_in[13],
      (const float*)d_in[15], (const float*)d_in[16], (const float*)d_in[17],
      (const float*)d_in[19], (const float*)d_in[5],  ws);

  sacq_wave<<<dim3(B / 128), dim3(256), 0, stream>>>(
      (const float*)d_in[0],  (const float*)d_in[1],  (const float*)d_in[2],
      (const float*)d_in[3],  (const float*)d_in[4],  (const float*)d_in[5],
      (const float*)d_in[7],  (const float*)d_in[8],  (const float*)d_in[9],
      (const float*)d_in[11], (const float*)d_in[12], (const float*)d_in[13],
      (const float*)d_in[15], (const float*)d_in[16], (const float*)d_in[17],
      (const float*)d_in[19], ws, (float*)d_out);
}

// Round 9
// 297.936 us; speedup vs baseline: 1.3486x; 1.0308x over previous
//
#include <hip/hip_runtime.h>
#include <math.h>

typedef __bf16 bf16x8 __attribute__((ext_vector_type(8)));
typedef __bf16 bf16x4 __attribute__((ext_vector_type(4)));
typedef float f32x4 __attribute__((ext_vector_type(4)));

// ---------------- weight conversion: fp32 -> bf16 frag-major in d_ws ----------
// Frag (kt,nt) = 32x16 block of B; lane L holds B[kt*32+(L>>4)*8+j][nt*16+(L&15)],
// j=0..7 -> one 16B chunk at L*16. Offsets (bf16 units): L1@0 (96x256, 48 frags),
// L2@24576 (256x128, 64), L3@57344 (128x64, 16), L4@65536 (64x128, 16; N 101->128 pad).
// Params packed LINEAR f32 at bf16-offset 73728 (quad index = float/4):
//   0..255 b1 | 256..511 g1 | 512..767 be1 | 768..895 b2 | 896..1023 g2
//   1024..1151 be2 | 1152..1215 b3 | 1216..1279 g3 | 1280..1343 be3
//   1344..1471 b4 (pad 0) | 1472..1599 qsup (pad 0).  Total ws: 153856 B.
__global__ void conv_weights(const float* __restrict__ W1, const float* __restrict__ W2,
                             const float* __restrict__ W3, const float* __restrict__ W4,
                             const float* __restrict__ b1, const float* __restrict__ g1, const float* __restrict__ be1,
                             const float* __restrict__ b2, const float* __restrict__ g2, const float* __restrict__ be2,
                             const float* __restrict__ b3, const float* __restrict__ g3, const float* __restrict__ be3,
                             const float* __restrict__ b4, const float* __restrict__ qsup,
                             __bf16* __restrict__ ws)
{
  if (blockIdx.x == 36) {
    float* Pp = (float*)(ws + 73728);
    const int t = threadIdx.x;
    Pp[t]       = b1[t];
    Pp[256 + t] = g1[t];
    Pp[512 + t] = be1[t];
    if (t < 128) {
      Pp[768 + t]  = b2[t];
      Pp[896 + t]  = g2[t];
      Pp[1024 + t] = be2[t];
      Pp[1344 + t] = (t < 101) ? b4[t]   : 0.f;
      Pp[1472 + t] = (t < 101) ? qsup[t] : 0.f;
    }
    if (t < 64) {
      Pp[1152 + t] = b3[t];
      Pp[1216 + t] = g3[t];
      Pp[1280 + t] = be3[t];
    }
    return;
  }
  const int f = blockIdx.x * 4 + (threadIdx.x >> 6);
  const int lane = threadIdx.x & 63;
  int f0, ntot, Ksrc, Nsrc, off;
  const float* W;
  if (f < 48)       { f0 = f;       ntot = 16; Ksrc = 80;  Nsrc = 256; W = W1; off = 0; }
  else if (f < 112) { f0 = f - 48;  ntot = 8;  Ksrc = 256; Nsrc = 128; W = W2; off = 24576; }
  else if (f < 128) { f0 = f - 112; ntot = 4;  Ksrc = 128; Nsrc = 64;  W = W3; off = 57344; }
  else              { f0 = f - 128; ntot = 8;  Ksrc = 64;  Nsrc = 101; W = W4; off = 65536; }
  const int kt = f0 / ntot, nt = f0 % ntot;
  const int q = lane >> 4, c = lane & 15;
  const int n = nt * 16 + c;
  bf16x8 v;
#pragma unroll
  for (int j = 0; j < 8; ++j) {
    const int k = kt * 32 + q * 8 + j;
    const float x = (k < Ksrc && n < Nsrc) ? W[k * Nsrc + n] : 0.f;
    v[j] = (__bf16)x;
  }
  ((bf16x8*)(ws + off))[f0 * 64 + lane] = v;
}

// ---------------- fused forward: out^T MFMA, 16 rows/wave, spill-free ---------
// From R6-R8: operand-swapped MFMA (weights=A, activations=B -> lane-local
// stats, bf16x4 stores, branch-free projection) is worth -11%; the 32-row
// variant's acc1[2][16]=128 regs forces spill at the 256-reg cap (R6/R8) and
// rolled-loop fixes wreck regalloc (R7). THIS ROUND: 16 rows/wave (rows/wave
// was measured neutral, R2 vs R5) ->
//   * acc1[16]=64 regs, L1 peak ~140: NO spill;
//   * all 1600 packed params staged to LDS once per block: every epilogue
//     param read becomes a broadcast ds_read_b128 (no L2 round-trips);
//   * L1 restored to depth-1 prefetch (double-buffered 6-frag chunks);
//   * LDS 41.5KB/block -> 3 blocks/CU (12 waves/CU, ~2x residency) with
//     __launch_bounds__(256,3).
//
// LDS layout (floats): params [0,1600) block-shared; per-wave region at
// 1600 + wv*2192: h1 [16][264] bf16 = floats [0,2112) (h2 [16][136], h3
// [16][72] overlay; layer-k writes data-depend on layer-(k-1) reads);
// proj [16][101] at +576 (L4 only; overlays dead h1/h2 tail; h3 [0,576)
// disjoint; fence pins the zero-stores after A4 reads).
// Block = (1600 + 4*2192)*4 = 41472 B -> 3 blocks/CU. Grid B/64 = 2048.

__global__ __launch_bounds__(256, 3)
void sacq_wave(const float* __restrict__ obs,  const float* __restrict__ act,
               const float* __restrict__ rew,  const float* __restrict__ boot,
               const float* __restrict__ disc, const float* __restrict__ qsup,
               const float* __restrict__ b1, const float* __restrict__ g1, const float* __restrict__ be1,
               const float* __restrict__ b2, const float* __restrict__ g2, const float* __restrict__ be2,
               const float* __restrict__ b3, const float* __restrict__ g3, const float* __restrict__ be3,
               const float* __restrict__ b4,
               const __bf16* __restrict__ ws,
               float* __restrict__ out)
{
  __shared__ __align__(16) float sm[10368];
  const int t = threadIdx.x;
  const int wv = t >> 6, lane = t & 63;
  const int q = lane >> 4, c = lane & 15;

  // ---- stage packed params (6.4KB) into LDS once per block
  {
    const float* Pg = (const float*)(const void*)(ws + 73728);
#pragma unroll
    for (int i = 0; i < 7; ++i) {
      const int idx = t + i * 256;
      if (idx < 1600) sm[idx] = Pg[idx];
    }
  }
  __syncthreads();
  const f32x4* P4 = (const f32x4*)sm;     // param quads, LDS-resident

  float* smw = sm + 1600 + wv * 2192;
  __bf16* h = (__bf16*)smw;               // h1/h2/h3 overlay
  float* proj = smw + 576;                // [16][101] (L4 only)
  const int row0w = blockIdx.x * 64 + wv * 16;
  const bf16x8* wsf = (const bf16x8*)ws;
  const int fq = 4 * q;                   // feature sub-offset within an m-tile

  // ================= Layer 1: out^T[256][16] = W1^T @ x^T, LN+SiLU ==========
  {
    bf16x8 A1[3];   // activation fragments (B operand): lane c holds row c
    {
      const float4* ob4 = (const float4*)(obs + (size_t)(row0w + c) * 60);
      const float4* ac4 = (const float4*)(act + (size_t)(row0w + c) * 20);
#pragma unroll
      for (int kt = 0; kt < 3; ++kt) {
        const int k0 = kt * 32 + q * 8;
        float v[8];
        if (k0 < 56) {
          const float4 a = ob4[k0 / 4], b = ob4[k0 / 4 + 1];
          v[0]=a.x; v[1]=a.y; v[2]=a.z; v[3]=a.w; v[4]=b.x; v[5]=b.y; v[6]=b.z; v[7]=b.w;
        } else if (k0 == 56) {
          const float4 a = ob4[14], b = ac4[0];
          v[0]=a.x; v[1]=a.y; v[2]=a.z; v[3]=a.w; v[4]=b.x; v[5]=b.y; v[6]=b.z; v[7]=b.w;
        } else if (k0 < 80) {
          const float4 a = ac4[(k0 - 60) / 4], b = ac4[(k0 - 60) / 4 + 1];
          v[0]=a.x; v[1]=a.y; v[2]=a.z; v[3]=a.w; v[4]=b.x; v[5]=b.y; v[6]=b.z; v[7]=b.w;
        } else {
#pragma unroll
          for (int j = 0; j < 8; ++j) v[j] = 0.f;
        }
#pragma unroll
        for (int j = 0; j < 8; ++j) A1[kt][j] = (__bf16)v[j];
      }
    }
    f32x4 acc1[16];
#pragma unroll
    for (int mt = 0; mt < 16; ++mt) acc1[mt] = P4[4 * mt + q];   // bias (LDS bcast)
    // 8 chunks of 2 m-tiles, depth-1 prefetch: MFMAs never eat a fresh load
    bf16x8 Wb[2][3][2];
#pragma unroll
    for (int kt = 0; kt < 3; ++kt)
#pragma unroll
      for (int j = 0; j < 2; ++j)
        Wb[0][kt][j] = wsf[(kt * 16 + j) * 64 + lane];
#pragma unroll
    for (int ch = 0; ch < 8; ++ch) {
      const int cur = ch & 1, nxt = cur ^ 1;
      if (ch + 1 < 8) {
#pragma unroll
        for (int kt = 0; kt < 3; ++kt)
#pragma unroll
          for (int j = 0; j < 2; ++j)
            Wb[nxt][kt][j] = wsf[(kt * 16 + (ch + 1) * 2 + j) * 64 + lane];
      }
#pragma unroll
      for (int kt = 0; kt < 3; ++kt)
#pragma unroll
        for (int j = 0; j < 2; ++j)
          acc1[ch * 2 + j] = __builtin_amdgcn_mfma_f32_16x16x32_bf16(Wb[cur][kt][j], A1[kt], acc1[ch * 2 + j], 0, 0, 0);
    }
    // LN stats: lane-local over 64 features + butterfly over q-lanes (2 shfl)
    float s = 0.f, s2 = 0.f;
#pragma unroll
    for (int mt = 0; mt < 16; ++mt)
#pragma unroll
      for (int r = 0; r < 4; ++r) { const float v = acc1[mt][r]; s += v; s2 += v * v; }
    s += __shfl_xor(s, 16); s2 += __shfl_xor(s2, 16);
    s += __shfl_xor(s, 32); s2 += __shfl_xor(s2, 32);
    const float mu = s * (1.f / 256.f);
    const float rs = rsqrtf(s2 * (1.f / 256.f) - mu * mu + 1e-5f);
#pragma unroll
    for (int mt = 0; mt < 16; ++mt) {
      const f32x4 g4  = P4[64 + 4 * mt + q];
      const f32x4 be4 = P4[128 + 4 * mt + q];
      bf16x4 o;
#pragma unroll
      for (int r = 0; r < 4; ++r) {
        float x = (acc1[mt][r] - mu) * rs * g4[r] + be4[r];
        x = x * __builtin_amdgcn_rcpf(1.f + __expf(-x));
        o[r] = (__bf16)x;
      }
      *(bf16x4*)(h + c * 264 + 16 * mt + fq) = o;
    }
  }

  // ================= Layer 2: out^T[128][16] = W2^T @ h1^T, LN+SiLU =========
  {
    f32x4 acc2[8];
#pragma unroll
    for (int mt = 0; mt < 8; ++mt) acc2[mt] = P4[192 + 4 * mt + q];
    bf16x8 W2f[2][8];
#pragma unroll
    for (int mt = 0; mt < 8; ++mt) W2f[0][mt] = wsf[3072 + mt * 64 + lane];
#pragma unroll
    for (int kt = 0; kt < 8; ++kt) {
      if (kt + 1 < 8) {
#pragma unroll
        for (int mt = 0; mt < 8; ++mt)
          W2f[(kt + 1) & 1][mt] = wsf[3072 + ((kt + 1) * 8 + mt) * 64 + lane];
      }
      const bf16x8 A2 = *(const bf16x8*)(h + c * 264 + kt * 32 + q * 8);
#pragma unroll
      for (int mt = 0; mt < 8; ++mt)
        acc2[mt] = __builtin_amdgcn_mfma_f32_16x16x32_bf16(W2f[kt & 1][mt], A2, acc2[mt], 0, 0, 0);
    }
    float s = 0.f, s2 = 0.f;
#pragma unroll
    for (int mt = 0; mt < 8; ++mt)
#pragma unroll
      for (int r = 0; r < 4; ++r) { const float v = acc2[mt][r]; s += v; s2 += v * v; }
    s += __shfl_xor(s, 16); s2 += __shfl_xor(s2, 16);
    s += __shfl_xor(s, 32); s2 += __shfl_xor(s2, 32);
    const float mu = s * (1.f / 128.f);
    const float rs = rsqrtf(s2 * (1.f / 128.f) - mu * mu + 1e-5f);
#pragma unroll
    for (int mt = 0; mt < 8; ++mt) {
      const f32x4 g4  = P4[224 + 4 * mt + q];
      const f32x4 be4 = P4[256 + 4 * mt + q];
      bf16x4 o;
#pragma unroll
      for (int r = 0; r < 4; ++r) {
        float x = (acc2[mt][r] - mu) * rs * g4[r] + be4[r];
        x = x * __builtin_amdgcn_rcpf(1.f + __expf(-x));
        o[r] = (__bf16)x;
      }
      *(bf16x4*)(h + c * 136 + 16 * mt + fq) = o;
    }
  }

  // ================= Layer 3: out^T[64][16] = W3^T @ h2^T, LN+SiLU ==========
  {
    bf16x8 W3f[4][4];
#pragma unroll
    for (int kt = 0; kt < 4; ++kt)
#pragma unroll
      for (int mt = 0; mt < 4; ++mt)
        W3f[kt][mt] = wsf[7168 + (kt * 4 + mt) * 64 + lane];
    f32x4 acc3[4];
#pragma unroll
    for (int mt = 0; mt < 4; ++mt) acc3[mt] = P4[288 + 4 * mt + q];
#pragma unroll
    for (int kt = 0; kt < 4; ++kt) {
      const bf16x8 A3 = *(const bf16x8*)(h + c * 136 + kt * 32 + q * 8);
#pragma unroll
      for (int mt = 0; mt < 4; ++mt)
        acc3[mt] = __builtin_amdgcn_mfma_f32_16x16x32_bf16(W3f[kt][mt], A3, acc3[mt], 0, 0, 0);
    }
    float s = 0.f, s2 = 0.f;
#pragma unroll
    for (int mt = 0; mt < 4; ++mt)
#pragma unroll
      for (int r = 0; r < 4; ++r) { const float v = acc3[mt][r]; s += v; s2 += v * v; }
    s += __shfl_xor(s, 16); s2 += __shfl_xor(s2, 16);
    s += __shfl_xor(s, 32); s2 += __shfl_xor(s2, 32);
    const float mu = s * (1.f / 64.f);
    const float rs = rsqrtf(s2 * (1.f / 64.f) - mu * mu + 1e-5f);
#pragma unroll
    for (int mt = 0; mt < 4; ++mt) {
      const f32x4 g4  = P4[304 + 4 * mt + q];
      const f32x4 be4 = P4[320 + 4 * mt + q];
      bf16x4 o;
#pragma unroll
      for (int r = 0; r < 4; ++r) {
        float x = (acc3[mt][r] - mu) * rs * g4[r] + be4[r];
        x = x * __builtin_amdgcn_rcpf(1.f + __expf(-x));
        o[r] = (__bf16)x;
      }
      *(bf16x4*)(h + c * 72 + 16 * mt + fq) = o;
    }
  }

  // ================= Layer 4 (101 feats) + softmax + projection =============
  {
    bf16x8 W4f[2][7];
#pragma unroll
    for (int kt = 0; kt < 2; ++kt)
#pragma unroll
      for (int mt = 0; mt < 7; ++mt)
        W4f[kt][mt] = wsf[8192 + (kt * 8 + mt) * 64 + lane];
    bf16x8 A4f[2];
#pragma unroll
    for (int kt = 0; kt < 2; ++kt)
      A4f[kt] = *(const bf16x8*)(h + c * 72 + kt * 32 + q * 8);

    // Fence, then zero proj (proj [576,2192) overlays only dead h1/h2 tail;
    // live h3 [0,576) disjoint; keep stores ordered after the A4f reads).
    asm volatile("" ::: "memory");
    {
      f32x4 z = {0.f, 0.f, 0.f, 0.f};
      f32x4* p4 = (f32x4*)proj;
      for (int i = lane; i < 404; i += 64) p4[i] = z;
    }

    f32x4 a4[7];
#pragma unroll
    for (int mt = 0; mt < 7; ++mt) a4[mt] = P4[336 + 4 * mt + q];
#pragma unroll
    for (int kt = 0; kt < 2; ++kt)
#pragma unroll
      for (int mt = 0; mt < 7; ++mt)
        a4[mt] = __builtin_amdgcn_mfma_f32_16x16x32_bf16(W4f[kt][mt], A4f[kt], a4[mt], 0, 0, 0);

    // softmax over the 101 features of this lane's batch row (lane-local + 2 shfl)
    float mx = -3.4e38f;
#pragma unroll
    for (int mt = 0; mt < 7; ++mt) {
#pragma unroll
      for (int r = 0; r < 4; ++r) {
        const bool ok = (mt < 6) | (fq + r < 5);
        if (ok) mx = fmaxf(mx, a4[mt][r]);
      }
    }
    mx = fmaxf(mx, __shfl_xor(mx, 16));
    mx = fmaxf(mx, __shfl_xor(mx, 32));
    float sp = 0.f;
#pragma unroll
    for (int mt = 0; mt < 7; ++mt) {
#pragma unroll
      for (int r = 0; r < 4; ++r) {
        const bool ok = (mt < 6) | (fq + r < 5);
        const float e = ok ? __expf(a4[mt][r] - mx) : 0.f;
        a4[mt][r] = e;
        sp += e;
      }
    }
    sp += __shfl_xor(sp, 16);
    sp += __shfl_xor(sp, 32);
    const float inv = __builtin_amdgcn_rcpf(sp);

    const int gr = row0w + c;
    const float rw = rew[gr];
    const float bd = boot[gr] * disc[gr];
    const int rb = c * 101;

    // categorical projection (branch-free index math; li in [0,99])
#pragma unroll
    for (int mt = 0; mt < 7; ++mt) {
      const f32x4 qs4 = P4[368 + 4 * mt + q];
#pragma unroll
      for (int r = 0; r < 4; ++r) {
        const bool ok = (mt < 6) | (fq + r < 5);
        if (ok) {
          const float p = a4[mt][r] * inv;
          float tz = rw + bd * qs4[r];
          tz = fminf(fmaxf(tz, -10.f), 10.f);
          const float b_ = tz * 5.f + 50.f;            // in [0,100]
          const float fl = fminf(floorf(b_), 99.f);    // in [0,99]
          const float frac = b_ - fl;                  // in [0,1]
          const float uw = p * frac;
          const float lw = p - uw;
          const int li = (int)fl;
          atomicAdd(&proj[rb + li], lw);
          atomicAdd(&proj[rb + li + 1], uw);
        }
      }
    }
  }

  // ---- coalesced float4 writeout of this wave's 16x101 block
  {
    const f32x4* p4 = (const f32x4*)proj;
    f32x4* o4 = (f32x4*)(out + (size_t)row0w * 101);
    for (int i = lane; i < 404; i += 64) o4[i] = p4[i];
  }
}

extern "C" void kernel_launch(void* const* d_in, const int* in_sizes, int n_in,
                              void* d_out, int out_size, void* d_ws, size_t ws_size,
                              hipStream_t stream)
{
  const int B = in_sizes[2];  // rewards: B elements
  __bf16* ws = (__bf16*)d_ws; // 153856 B used

  conv_weights<<<dim3(37), dim3(256), 0, stream>>>(
      (const float*)d_in[6],  (const float*)d_in[10], (const float*)d_in[14],
      (const float*)d_in[18],
      (const float*)d_in[7],  (const float*)d_in[8],  (const float*)d_in[9],
      (const float*)d_in[11], (const float*)d_in[12], (const float*)d_in[13],
      (const float*)d_in[15], (const float*)d_in[16], (const float*)d_in[17],
      (const float*)d_in[19], (const float*)d_in[5],  ws);

  sacq_wave<<<dim3(B / 64), dim3(256), 0, stream>>>(
      (const float*)d_in[0],  (const float*)d_in[1],  (const float*)d_in[2],
      (const float*)d_in[3],  (const float*)d_in[4],  (const float*)d_in[5],
      (const float*)d_in[7],  (const float*)d_in[8],  (const float*)d_in[9],
      (const float*)d_in[11], (const float*)d_in[12], (const float*)d_in[13],
      (const float*)d_in[15], (const float*)d_in[16], (const float*)d_in[17],
      (const float*)d_in[19], ws, (float*)d_out);
}

// Round 10
// 296.438 us; speedup vs baseline: 1.3555x; 1.0051x over previous
//
#include <hip/hip_runtime.h>
#include <math.h>

typedef __bf16 bf16x8 __attribute__((ext_vector_type(8)));
typedef __bf16 bf16x4 __attribute__((ext_vector_type(4)));
typedef float f32x4 __attribute__((ext_vector_type(4)));

// ---------------- weight conversion: fp32 -> bf16 frag-major in d_ws ----------
// Frag (kt,nt) = 32x16 block of B; lane L holds B[kt*32+(L>>4)*8+j][nt*16+(L&15)],
// j=0..7 -> one 16B chunk at L*16. Offsets (bf16 units): L1@0 (96x256, 48 frags),
// L2@24576 (256x128, 64), L3@57344 (128x64, 16), L4@65536 (64x128, 16; N 101->128 pad).
// Params packed LINEAR f32 at bf16-offset 73728 (b1 NOT staged — read from global):
//   float idx 0..255 g1 | 256..511 be1 | 512..639 b2 | 640..767 g2 | 768..895 be2
//   896..959 b3 | 960..1023 g3 | 1024..1087 be3 | 1088..1215 b4 (pad 0)
//   1216..1343 qsup (pad 0).   Total staged params: 1344 f = 5376 B.
__global__ void conv_weights(const float* __restrict__ W1, const float* __restrict__ W2,
                             const float* __restrict__ W3, const float* __restrict__ W4,
                             const float* __restrict__ b1, const float* __restrict__ g1, const float* __restrict__ be1,
                             const float* __restrict__ b2, const float* __restrict__ g2, const float* __restrict__ be2,
                             const float* __restrict__ b3, const float* __restrict__ g3, const float* __restrict__ be3,
                             const float* __restrict__ b4, const float* __restrict__ qsup,
                             __bf16* __restrict__ ws)
{
  if (blockIdx.x == 36) {
    float* Pp = (float*)(ws + 73728);
    const int t = threadIdx.x;
    Pp[t]       = g1[t];
    Pp[256 + t] = be1[t];
    if (t < 128) {
      Pp[512 + t]  = b2[t];
      Pp[640 + t]  = g2[t];
      Pp[768 + t]  = be2[t];
      Pp[1088 + t] = (t < 101) ? b4[t]   : 0.f;
      Pp[1216 + t] = (t < 101) ? qsup[t] : 0.f;
    }
    if (t < 64) {
      Pp[896 + t]  = b3[t];
      Pp[960 + t]  = g3[t];
      Pp[1024 + t] = be3[t];
    }
    return;
  }
  const int f = blockIdx.x * 4 + (threadIdx.x >> 6);
  const int lane = threadIdx.x & 63;
  int f0, ntot, Ksrc, Nsrc, off;
  const float* W;
  if (f < 48)       { f0 = f;       ntot = 16; Ksrc = 80;  Nsrc = 256; W = W1; off = 0; }
  else if (f < 112) { f0 = f - 48;  ntot = 8;  Ksrc = 256; Nsrc = 128; W = W2; off = 24576; }
  else if (f < 128) { f0 = f - 112; ntot = 4;  Ksrc = 128; Nsrc = 64;  W = W3; off = 57344; }
  else              { f0 = f - 128; ntot = 8;  Ksrc = 64;  Nsrc = 101; W = W4; off = 65536; }
  const int kt = f0 / ntot, nt = f0 % ntot;
  const int q = lane >> 4, c = lane & 15;
  const int n = nt * 16 + c;
  bf16x8 v;
#pragma unroll
  for (int j = 0; j < 8; ++j) {
    const int k = kt * 32 + q * 8 + j;
    const float x = (k < Ksrc && n < Nsrc) ? W[k * Nsrc + n] : 0.f;
    v[j] = (__bf16)x;
  }
  ((bf16x8*)(ws + off))[f0 * 64 + lane] = v;
}

// ---------------- fused forward: out^T MFMA, 16 rows/wave, op-count shaved ----
// R9 structure (192us): swapped MFMA (weights=A -> lane-local stats, bf16x4
// stores, branch-free projection), params in LDS, depth-1 L1 prefetch, no
// spill. THIS ROUND (op-count is the only lever with consistent signal):
//   * LN epilogue folded: per m-tile rsg=rs*g, off=be-mu*rsg -> 1 FMA/element
//     (was sub+mul+mul+add); exact-fp32 reassociation only.
//   * fmed3 clamp + explicit fmaf in the projection.
//   * b1 dropped from LDS params (16 broadcast global loads at init; R2 proved
//     this latency class null) -> block LDS 41472->40448 B -> 4 blocks/CU
//     (16 waves/CU) with __launch_bounds__(256,4).
//
// LDS layout (floats): params [0,1344) block-shared; per-wave region at
// 1344 + wv*2192: h1 [16][264] bf16 = floats [0,2112) (h2 [16][136], h3
// [16][72] overlay; layer-k writes data-depend on layer-(k-1) reads);
// proj [16][101] at +576 (L4 only; overlays dead h1/h2 tail; h3 [0,576)
// disjoint; fence pins the zero-stores after A4 reads).
// Block = (1344 + 4*2192)*4 = 40448 B -> 4 blocks/CU. Grid B/64 = 2048.

__global__ __launch_bounds__(256, 4)
void sacq_wave(const float* __restrict__ obs,  const float* __restrict__ act,
               const float* __restrict__ rew,  const float* __restrict__ boot,
               const float* __restrict__ disc, const float* __restrict__ qsup,
               const float* __restrict__ b1, const float* __restrict__ g1, const float* __restrict__ be1,
               const float* __restrict__ b2, const float* __restrict__ g2, const float* __restrict__ be2,
               const float* __restrict__ b3, const float* __restrict__ g3, const float* __restrict__ be3,
               const float* __restrict__ b4,
               const __bf16* __restrict__ ws,
               float* __restrict__ out)
{
  __shared__ __align__(16) float sm[10112];
  const int t = threadIdx.x;
  const int wv = t >> 6, lane = t & 63;
  const int q = lane >> 4, c = lane & 15;

  // ---- stage packed params (5.4KB) into LDS once per block
  {
    const float* Pg = (const float*)(const void*)(ws + 73728);
#pragma unroll
    for (int i = 0; i < 6; ++i) {
      const int idx = t + i * 256;
      if (idx < 1344) sm[idx] = Pg[idx];
    }
  }
  __syncthreads();
  const f32x4* P4 = (const f32x4*)sm;     // param quads, LDS-resident

  float* smw = sm + 1344 + wv * 2192;
  __bf16* h = (__bf16*)smw;               // h1/h2/h3 overlay
  float* proj = smw + 576;                // [16][101] (L4 only)
  const int row0w = blockIdx.x * 64 + wv * 16;
  const bf16x8* wsf = (const bf16x8*)ws;
  const int fq = 4 * q;                   // feature sub-offset within an m-tile

  // ================= Layer 1: out^T[256][16] = W1^T @ x^T, LN+SiLU ==========
  {
    // bias from global (broadcast loads; latency class proven null in R2)
    f32x4 acc1[16];
#pragma unroll
    for (int mt = 0; mt < 16; ++mt)
      acc1[mt] = *(const f32x4*)(b1 + 16 * mt + fq);

    bf16x8 A1[3];   // activation fragments (B operand): lane c holds row c
    {
      const float4* ob4 = (const float4*)(obs + (size_t)(row0w + c) * 60);
      const float4* ac4 = (const float4*)(act + (size_t)(row0w + c) * 20);
#pragma unroll
      for (int kt = 0; kt < 3; ++kt) {
        const int k0 = kt * 32 + q * 8;
        float v[8];
        if (k0 < 56) {
          const float4 a = ob4[k0 / 4], b = ob4[k0 / 4 + 1];
          v[0]=a.x; v[1]=a.y; v[2]=a.z; v[3]=a.w; v[4]=b.x; v[5]=b.y; v[6]=b.z; v[7]=b.w;
        } else if (k0 == 56) {
          const float4 a = ob4[14], b = ac4[0];
          v[0]=a.x; v[1]=a.y; v[2]=a.z; v[3]=a.w; v[4]=b.x; v[5]=b.y; v[6]=b.z; v[7]=b.w;
        } else if (k0 < 80) {
          const float4 a = ac4[(k0 - 60) / 4], b = ac4[(k0 - 60) / 4 + 1];
          v[0]=a.x; v[1]=a.y; v[2]=a.z; v[3]=a.w; v[4]=b.x; v[5]=b.y; v[6]=b.z; v[7]=b.w;
        } else {
#pragma unroll
          for (int j = 0; j < 8; ++j) v[j] = 0.f;
        }
#pragma unroll
        for (int j = 0; j < 8; ++j) A1[kt][j] = (__bf16)v[j];
      }
    }
    // 8 chunks of 2 m-tiles, depth-1 prefetch: MFMAs never eat a fresh load
    bf16x8 Wb[2][3][2];
#pragma unroll
    for (int kt = 0; kt < 3; ++kt)
#pragma unroll
      for (int j = 0; j < 2; ++j)
        Wb[0][kt][j] = wsf[(kt * 16 + j) * 64 + lane];
#pragma unroll
    for (int ch = 0; ch < 8; ++ch) {
      const int cur = ch & 1, nxt = cur ^ 1;
      if (ch + 1 < 8) {
#pragma unroll
        for (int kt = 0; kt < 3; ++kt)
#pragma unroll
          for (int j = 0; j < 2; ++j)
            Wb[nxt][kt][j] = wsf[(kt * 16 + (ch + 1) * 2 + j) * 64 + lane];
      }
#pragma unroll
      for (int kt = 0; kt < 3; ++kt)
#pragma unroll
        for (int j = 0; j < 2; ++j)
          acc1[ch * 2 + j] = __builtin_amdgcn_mfma_f32_16x16x32_bf16(Wb[cur][kt][j], A1[kt], acc1[ch * 2 + j], 0, 0, 0);
    }
    // LN stats: lane-local over 64 features + butterfly over q-lanes (2 shfl)
    float s = 0.f, s2 = 0.f;
#pragma unroll
    for (int mt = 0; mt < 16; ++mt)
#pragma unroll
      for (int r = 0; r < 4; ++r) { const float v = acc1[mt][r]; s += v; s2 += v * v; }
    s += __shfl_xor(s, 16); s2 += __shfl_xor(s2, 16);
    s += __shfl_xor(s, 32); s2 += __shfl_xor(s2, 32);
    const float mu = s * (1.f / 256.f);
    const float rs = rsqrtf(s2 * (1.f / 256.f) - mu * mu + 1e-5f);
#pragma unroll
    for (int mt = 0; mt < 16; ++mt) {
      const f32x4 g4  = P4[4 * mt + q];
      const f32x4 be4 = P4[64 + 4 * mt + q];
      bf16x4 o;
#pragma unroll
      for (int r = 0; r < 4; ++r) {
        const float rsg = rs * g4[r];
        const float off = fmaf(-mu, rsg, be4[r]);
        float x = fmaf(acc1[mt][r], rsg, off);
        x = x * __builtin_amdgcn_rcpf(1.f + __expf(-x));
        o[r] = (__bf16)x;
      }
      *(bf16x4*)(h + c * 264 + 16 * mt + fq) = o;
    }
  }

  // ================= Layer 2: out^T[128][16] = W2^T @ h1^T, LN+SiLU =========
  {
    f32x4 acc2[8];
#pragma unroll
    for (int mt = 0; mt < 8; ++mt) acc2[mt] = P4[128 + 4 * mt + q];
    bf16x8 W2f[2][8];
#pragma unroll
    for (int mt = 0; mt < 8; ++mt) W2f[0][mt] = wsf[3072 + mt * 64 + lane];
#pragma unroll
    for (int kt = 0; kt < 8; ++kt) {
      if (kt + 1 < 8) {
#pragma unroll
        for (int mt = 0; mt < 8; ++mt)
          W2f[(kt + 1) & 1][mt] = wsf[3072 + ((kt + 1) * 8 + mt) * 64 + lane];
      }
      const bf16x8 A2 = *(const bf16x8*)(h + c * 264 + kt * 32 + q * 8);
#pragma unroll
      for (int mt = 0; mt < 8; ++mt)
        acc2[mt] = __builtin_amdgcn_mfma_f32_16x16x32_bf16(W2f[kt & 1][mt], A2, acc2[mt], 0, 0, 0);
    }
    float s = 0.f, s2 = 0.f;
#pragma unroll
    for (int mt = 0; mt < 8; ++mt)
#pragma unroll
      for (int r = 0; r < 4; ++r) { const float v = acc2[mt][r]; s += v; s2 += v * v; }
    s += __shfl_xor(s, 16); s2 += __shfl_xor(s2, 16);
    s += __shfl_xor(s, 32); s2 += __shfl_xor(s2, 32);
    const float mu = s * (1.f / 128.f);
    const float rs = rsqrtf(s2 * (1.f / 128.f) - mu * mu + 1e-5f);
#pragma unroll
    for (int mt = 0; mt < 8; ++mt) {
      const f32x4 g4  = P4[160 + 4 * mt + q];
      const f32x4 be4 = P4[192 + 4 * mt + q];
      bf16x4 o;
#pragma unroll
      for (int r = 0; r < 4; ++r) {
        const float rsg = rs * g4[r];
        const float off = fmaf(-mu, rsg, be4[r]);
        float x = fmaf(acc2[mt][r], rsg, off);
        x = x * __builtin_amdgcn_rcpf(1.f + __expf(-x));
        o[r] = (__bf16)x;
      }
      *(bf16x4*)(h + c * 136 + 16 * mt + fq) = o;
    }
  }

  // ================= Layer 3: out^T[64][16] = W3^T @ h2^T, LN+SiLU ==========
  {
    bf16x8 W3f[4][4];
#pragma unroll
    for (int kt = 0; kt < 4; ++kt)
#pragma unroll
      for (int mt = 0; mt < 4; ++mt)
        W3f[kt][mt] = wsf[7168 + (kt * 4 + mt) * 64 + lane];
    f32x4 acc3[4];
#pragma unroll
    for (int mt = 0; mt < 4; ++mt) acc3[mt] = P4[224 + 4 * mt + q];
#pragma unroll
    for (int kt = 0; kt < 4; ++kt) {
      const bf16x8 A3 = *(const bf16x8*)(h + c * 136 + kt * 32 + q * 8);
#pragma unroll
      for (int mt = 0; mt < 4; ++mt)
        acc3[mt] = __builtin_amdgcn_mfma_f32_16x16x32_bf16(W3f[kt][mt], A3, acc3[mt], 0, 0, 0);
    }
    float s = 0.f, s2 = 0.f;
#pragma unroll
    for (int mt = 0; mt < 4; ++mt)
#pragma unroll
      for (int r = 0; r < 4; ++r) { const float v = acc3[mt][r]; s += v; s2 += v * v; }
    s += __shfl_xor(s, 16); s2 += __shfl_xor(s2, 16);
    s += __shfl_xor(s, 32); s2 += __shfl_xor(s2, 32);
    const float mu = s * (1.f / 64.f);
    const float rs = rsqrtf(s2 * (1.f / 64.f) - mu * mu + 1e-5f);
#pragma unroll
    for (int mt = 0; mt < 4; ++mt) {
      const f32x4 g4  = P4[240 + 4 * mt + q];
      const f32x4 be4 = P4[256 + 4 * mt + q];
      bf16x4 o;
#pragma unroll
      for (int r = 0; r < 4; ++r) {
        const float rsg = rs * g4[r];
        const float off = fmaf(-mu, rsg, be4[r]);
        float x = fmaf(acc3[mt][r], rsg, off);
        x = x * __builtin_amdgcn_rcpf(1.f + __expf(-x));
        o[r] = (__bf16)x;
      }
      *(bf16x4*)(h + c * 72 + 16 * mt + fq) = o;
    }
  }

  // ================= Layer 4 (101 feats) + softmax + projection =============
  {
    bf16x8 W4f[2][7];
#pragma unroll
    for (int kt = 0; kt < 2; ++kt)
#pragma unroll
      for (int mt = 0; mt < 7; ++mt)
        W4f[kt][mt] = wsf[8192 + (kt * 8 + mt) * 64 + lane];
    bf16x8 A4f[2];
#pragma unroll
    for (int kt = 0; kt < 2; ++kt)
      A4f[kt] = *(const bf16x8*)(h + c * 72 + kt * 32 + q * 8);

    // Fence, then zero proj (proj [576,2192) overlays only dead h1/h2 tail;
    // live h3 [0,576) disjoint; keep stores ordered after the A4f reads).
    asm volatile("" ::: "memory");
    {
      f32x4 z = {0.f, 0.f, 0.f, 0.f};
      f32x4* p4 = (f32x4*)proj;
      for (int i = lane; i < 404; i += 64) p4[i] = z;
    }

    f32x4 a4[7];
#pragma unroll
    for (int mt = 0; mt < 7; ++mt) a4[mt] = P4[272 + 4 * mt + q];
#pragma unroll
    for (int kt = 0; kt < 2; ++kt)
#pragma unroll
      for (int mt = 0; mt < 7; ++mt)
        a4[mt] = __builtin_amdgcn_mfma_f32_16x16x32_bf16(W4f[kt][mt], A4f[kt], a4[mt], 0, 0, 0);

    // softmax over the 101 features of this lane's batch row (lane-local + 2 shfl)
    float mx = -3.4e38f;
#pragma unroll
    for (int mt = 0; mt < 7; ++mt) {
#pragma unroll
      for (int r = 0; r < 4; ++r) {
        const bool ok = (mt < 6) | (fq + r < 5);
        if (ok) mx = fmaxf(mx, a4[mt][r]);
      }
    }
    mx = fmaxf(mx, __shfl_xor(mx, 16));
    mx = fmaxf(mx, __shfl_xor(mx, 32));
    float sp = 0.f;
#pragma unroll
    for (int mt = 0; mt < 7; ++mt) {
#pragma unroll
      for (int r = 0; r < 4; ++r) {
        const bool ok = (mt < 6) | (fq + r < 5);
        const float e = ok ? __expf(a4[mt][r] - mx) : 0.f;
        a4[mt][r] = e;
        sp += e;
      }
    }
    sp += __shfl_xor(sp, 16);
    sp += __shfl_xor(sp, 32);
    const float inv = __builtin_amdgcn_rcpf(sp);

    const int gr = row0w + c;
    const float rw = rew[gr];
    const float bd = boot[gr] * disc[gr];
    const int rb = c * 101;

    // categorical projection (branch-free index math; li in [0,99])
#pragma unroll
    for (int mt = 0; mt < 7; ++mt) {
      const f32x4 qs4 = P4[304 + 4 * mt + q];
#pragma unroll
      for (int r = 0; r < 4; ++r) {
        const bool ok = (mt < 6) | (fq + r < 5);
        if (ok) {
          const float p = a4[mt][r] * inv;
          const float tz = __builtin_amdgcn_fmed3f(fmaf(bd, qs4[r], rw), -10.f, 10.f);
          const float b_ = fmaf(tz, 5.f, 50.f);          // in [0,100]
          const float fl = fminf(floorf(b_), 99.f);      // in [0,99]
          const float frac = b_ - fl;                    // in [0,1]
          const float uw = p * frac;
          const float lw = p - uw;
          const int li = (int)fl;
          atomicAdd(&proj[rb + li], lw);
          atomicAdd(&proj[rb + li + 1], uw);
        }
      }
    }
  }

  // ---- coalesced float4 writeout of this wave's 16x101 block
  {
    const f32x4* p4 = (const f32x4*)proj;
    f32x4* o4 = (f32x4*)(out + (size_t)row0w * 101);
    for (int i = lane; i < 404; i += 64) o4[i] = p4[i];
  }
}

extern "C" void kernel_launch(void* const* d_in, const int* in_sizes, int n_in,
                              void* d_out, int out_size, void* d_ws, size_t ws_size,
                              hipStream_t stream)
{
  const int B = in_sizes[2];  // rewards: B elements
  __bf16* ws = (__bf16*)d_ws; // 147456 + 5376 = 152832 B used

  conv_weights<<<dim3(37), dim3(256), 0, stream>>>(
      (const float*)d_in[6],  (const float*)d_in[10], (const float*)d_in[14],
      (const float*)d_in[18],
      (const float*)d_in[7],  (const float*)d_in[8],  (const float*)d_in[9],
      (const float*)d_in[11], (const float*)d_in[12], (const float*)d_in[13],
      (const float*)d_in[15], (const float*)d_in[16], (const float*)d_in[17],
      (const float*)d_in[19], (const float*)d_in[5],  ws);

  sacq_wave<<<dim3(B / 64), dim3(256), 0, stream>>>(
      (const float*)d_in[0],  (const float*)d_in[1],  (const float*)d_in[2],
      (const float*)d_in[3],  (const float*)d_in[4],  (const float*)d_in[5],
      (const float*)d_in[7],  (const float*)d_in[8],  (const float*)d_in[9],
      (const float*)d_in[11], (const float*)d_in[12], (const float*)d_in[13],
      (const float*)d_in[15], (const float*)d_in[16], (const float*)d_in[17],
      (const float*)d_in[19], ws, (float*)d_out);
}